// Round 8
// baseline (248.330 us; speedup 1.0000x reference)
//
#include <hip/hip_runtime.h>

// NHWC conv 3x3 stride-1 SAME: x[16,128,128,64] f32, w[3,3,64,128] f32,
// bias[128] f32 -> out[16,128,128,128] f32.
// Implicit GEMM, bf16 MFMA 16x16x32.
// Round 10: B fully REGISTER-RESIDENT. R9 geometry kept (half-row blocks,
// 64px x 128co, 4 waves of 128px->32co... i.e. each wave 64px x 32co,
// 144 MFMA/wave, 25.3KB LDS, predicated borders, XCD remap, same stores)
// but the per-wave B slice (18 steps x 2 tj = 36 x 16B = 144 VGPR) is
// loaded ONCE before the staging barrier and never re-loaded: the MFMA
// loop contains zero global loads. A-fragments get a full 1-step-ahead
// prefetch (ac/an named arrays, all indices compile-time).
// __launch_bounds__(256,2): ~228 unified regs/lane fits without spill;
// occupancy ~8 waves/CU (rounds 5/6/9 proved TLP is not the bottleneck).

#define HH 128
#define WW 128
#define CIN 64
#define COUT 128

typedef __attribute__((ext_vector_type(8))) short v8s;   // 8 bf16 = 16 B
typedef __attribute__((ext_vector_type(4))) float v4f;   // MFMA C/D

#define ROW_CHUNKS 528             // 66 px * 8 chunks(16B) per px
#define WS_NEEDED  (9u * CIN * COUT * 2u)   // transposed bf16 weights

static __device__ __forceinline__ unsigned short f2bf(float f) {
    unsigned int u = __float_as_uint(f);
    unsigned int r = (u + 0x7fffu + ((u >> 16) & 1u)) >> 16;   // RNE
    return (unsigned short)r;
}

// ---- pre-pass: w[tap][ci][co] fp32 -> wt2[tap][kc][co][ci'] bf16 ----
// ci = kc*32 + ci'; per (tap,kc) a 128co x 32ci' panel, co-major.
__global__ __launch_bounds__(256) void cvt_w(const float* __restrict__ wgt,
                                             unsigned short* __restrict__ wt) {
    int idx = blockIdx.x * 256 + threadIdx.x;   // < 9*64*128 = 73728
    if (idx >= 9 * CIN * COUT) return;
    int co  = idx & (COUT - 1);
    int ci  = (idx >> 7) & (CIN - 1);
    int tap = idx >> 13;
    int kc  = ci >> 5;
    int cl  = ci & 31;
    wt[((tap * 2 + kc) * COUT + co) * 32 + cl] = f2bf(wgt[idx]);
}

// ---- main: half-row implicit-GEMM MFMA conv, register-resident B ----
__global__ __launch_bounds__(256, 2) void conv_mfma(
    const float* __restrict__ x,            // fp32 [16,128,128,64]
    const unsigned short* __restrict__ wt,  // bf16 [9][2][128][32]
    const float* __restrict__ bias,
    float* __restrict__ out) {
    __shared__ v8s smem[3 * ROW_CHUNKS];    // 25,344 B

    // XCD-aware remap: 4096 blocks, 512 consecutive logicals per XCD
    int bid = blockIdx.x;                   // 0..4095
    int logical = ((bid & 7) << 9) | (bid >> 3);
    int wh = logical & 1;                   // which W half
    int h  = (logical >> 1) & (HH - 1);
    int n  = logical >> 8;
    int w0 = wh << 6;                       // 0 or 64

    int tid  = threadIdx.x;
    int lane = tid & 63;
    int wid  = tid >> 6;           // 0..3 = cout quarter
    int l15  = lane & 15;
    int quad = lane >> 4;

    // ---- B: load the wave's ENTIRE weight slice into registers ----
    // per lane: 36 frags (18 steps x 2 tj), 16B each = 144 VGPRs.
    // Issued first so the whole staging phase + barrier covers the latency.
    const unsigned short* wlane = wt + ((size_t)(wid * 32 + l15)) * 32 + quad * 8;
    v8s breg[36];
    #pragma unroll
    for (int s = 0; s < 18; ++s) {
        breg[2 * s]     = *(const v8s*)(wlane + s * 4096);
        breg[2 * s + 1] = *(const v8s*)(wlane + s * 4096 + 512);
    }

    // ---- stage 3 input rows: fp32 global -> bf16 LDS (swizzled) ----
    // Row covers global px [w0-1, w0+64]; out-of-image chunks -> 0.
    #pragma unroll
    for (int dh = 0; dh < 3; ++dh) {
        int ih = h + dh - 1;
        bool rowok = (ih >= 0) && (ih < HH);       // block-uniform
        const float* rowf = x + ((size_t)(n * HH + (rowok ? ih : 0))) * WW * CIN;
        v8s* dst = smem + dh * ROW_CHUNKS;
        #pragma unroll
        for (int k = 0; k < 3; ++k) {
            int c = tid + (k << 8);                // 0..767, keep < 528
            if (c < ROW_CHUNKS) {
                int lp = c >> 3;                   // local px 0..65
                int gp = w0 - 1 + lp;              // global px -1..128
                v8s ch = (v8s)(short)0;
                if (rowok && gp >= 0 && gp < WW) {
                    const float* p = rowf + gp * CIN + (c & 7) * 8;
                    float4 a = *(const float4*)p;
                    float4 b = *(const float4*)(p + 4);
                    ch[0] = (short)f2bf(a.x); ch[1] = (short)f2bf(a.y);
                    ch[2] = (short)f2bf(a.z); ch[3] = (short)f2bf(a.w);
                    ch[4] = (short)f2bf(b.x); ch[5] = (short)f2bf(b.y);
                    ch[6] = (short)f2bf(b.z); ch[7] = (short)f2bf(b.w);
                }
                dst[c ^ (lp & 7)] = ch;            // xor-swizzle within px
            }
        }
    }

    float bv[2];
    bv[0] = bias[wid * 32 + l15];
    bv[1] = bias[wid * 32 + 16 + l15];

    __syncthreads();

    v4f acc[4][2];
    #pragma unroll
    for (int i = 0; i < 4; ++i)
        #pragma unroll
        for (int j = 0; j < 2; ++j) acc[i][j] = (v4f)0.f;

    // ---- 18 static steps: tap = s>>1 (dh=tap/3, dw=tap%3), kc = s&1.
    //      Zero global loads inside; A prefetched one FULL step ahead. ----
    // A addr for step s: lp = l15 + ti*16 + dw ; chunk = lp*8 + kc*4 + quad,
    //                    swizzle key = lp & 7 (ti-invariant).
#define LOADA(dst, ss) do {                                            \
        const int tap_ = (ss) >> 1;                                    \
        const int dh_  = tap_ / 3;                                     \
        const int dw_  = tap_ % 3;                                     \
        const int kc_  = (ss) & 1;                                     \
        const v8s* srow_ = smem + dh_ * ROW_CHUNKS;                    \
        const int lp0_ = l15 + dw_;                                    \
        const int sw_  = lp0_ & 7;                                     \
        const int c0_  = lp0_ * 8 + kc_ * 4 + quad;                    \
        dst[0] = srow_[(c0_ + 0 * 128) ^ sw_];                         \
        dst[1] = srow_[(c0_ + 1 * 128) ^ sw_];                         \
        dst[2] = srow_[(c0_ + 2 * 128) ^ sw_];                         \
        dst[3] = srow_[(c0_ + 3 * 128) ^ sw_];                         \
    } while (0)

    v8s ac[4], an[4];
    LOADA(ac, 0);
    #pragma unroll
    for (int s = 0; s < 18; ++s) {
        if (s < 17) LOADA(an, s + 1);              // next step's A in flight

        #pragma unroll
        for (int ti = 0; ti < 4; ++ti) {
            acc[ti][0] = __builtin_amdgcn_mfma_f32_16x16x32_bf16(
                ac[ti], breg[2 * s], acc[ti][0], 0, 0, 0);
            acc[ti][1] = __builtin_amdgcn_mfma_f32_16x16x32_bf16(
                ac[ti], breg[2 * s + 1], acc[ti][1], 0, 0, 0);
        }

        if (s < 17) {
            #pragma unroll
            for (int t = 0; t < 4; ++t) ac[t] = an[t];   // reg rename
        }
    }
#undef LOADA

    const float* __restrict__ ob =
        out + ((size_t)(n * HH + h) * WW + w0) * COUT + wid * 32 + l15;
    #pragma unroll
    for (int ti = 0; ti < 4; ++ti) {
        #pragma unroll
        for (int r = 0; r < 4; ++r) {
            int p = ti * 16 + quad * 4 + r;              // C/D: row=quad*4+reg
            float* op = (float*)ob + (size_t)p * COUT;
            op[0]  = acc[ti][0][r] + bv[0];
            op[16] = acc[ti][1][r] + bv[1];
        }
    }
}

// ---- fallback (direct conv) if workspace is too small ----
__global__ __launch_bounds__(256) void conv3x3_direct(
    const float* __restrict__ x, const float* __restrict__ wgt,
    const float* __restrict__ bias, float* __restrict__ out) {
    int idx = blockIdx.x * 256 + threadIdx.x;
    int co = idx & (COUT - 1);
    int w  = (idx >> 7) & (WW - 1);
    int h  = (idx >> 14) & (HH - 1);
    int n  = idx >> 21;
    float acc = bias[co];
    #pragma unroll
    for (int kh = 0; kh < 3; ++kh) {
        int ih = h + kh - 1;
        if (ih < 0 || ih >= HH) continue;
        #pragma unroll
        for (int kw = 0; kw < 3; ++kw) {
            int iw = w + kw - 1;
            if (iw < 0 || iw >= WW) continue;
            const float* xp = x + (((size_t)(n * HH + ih) * WW + iw) * CIN);
            const float* wp = wgt + ((size_t)((kh * 3 + kw) * CIN)) * COUT + co;
            #pragma unroll 8
            for (int ci = 0; ci < CIN; ++ci)
                acc = fmaf(xp[ci], wp[(size_t)ci * COUT], acc);
        }
    }
    out[idx] = acc;
}

extern "C" void kernel_launch(void* const* d_in, const int* in_sizes, int n_in,
                              void* d_out, int out_size, void* d_ws, size_t ws_size,
                              hipStream_t stream) {
    const float* x    = (const float*)d_in[0];
    const float* wgt  = (const float*)d_in[1];
    const float* bias = (const float*)d_in[2];
    float* out = (float*)d_out;

    if (ws_size < (size_t)WS_NEEDED) {
        int blocks = (out_size + 255) / 256;
        conv3x3_direct<<<blocks, 256, 0, stream>>>(x, wgt, bias, out);
        return;
    }

    unsigned short* wt = (unsigned short*)d_ws;
    cvt_w<<<(9 * CIN * COUT + 255) / 256, 256, 0, stream>>>(wgt, wt);
    conv_mfma<<<16 * HH * 2, 256, 0, stream>>>(x, wt, bias, out);
}